// Round 4
// baseline (1671.959 us; speedup 1.0000x reference)
//
#include <hip/hip_runtime.h>
#include <hip/hip_bf16.h>
#include <hip/hip_fp16.h>
#include <cstdint>
#include <cstddef>

// Problem constants
#define B_ROWS 32768
#define DIM    256
#define NBLK64 128          // 64-wide column blocks per row (8192/64)
// Keys are built from BIASED sims (acc initialized to +2.0, so key value = sim+2 in [1,3]).
// Margin audit: 2*eps_f16 (2.26e-3) + 19-bit key truncation at magnitude ~3 (4.9e-4)
//             + biased-accum rounding (~1e-5)  =>  2.76e-3 < CERT_M = 3e-3.
#define CERT_M 3.0e-3f
#define PRE_M  3.0e-3f

typedef _Float16 f16x8 __attribute__((ext_vector_type(8)));
typedef float    f32x4 __attribute__((ext_vector_type(4)));
typedef unsigned short u16x8 __attribute__((ext_vector_type(8)));

// ---- workspace layout (bytes) ----
#define WS_XBF     ((size_t)0)                    // 32768*256*2 = 16 MB (f16 normalized x)
#define WS_CBBF    ((size_t)16777216)             //  8192*256*2 =  4 MB (f16 normalized cb)
#define WS_TOPINFO ((size_t)20971520)             // 32768*128*8 = 32 MB {u32 k1, u32 k2}
#define WS_CNORM   ((size_t)54525952)             //  8192*8     = 64 KB (fp64 inverse norms)
#define WS_LPART   ((size_t)54591488)             //  8192*4     = 32 KB loss partials

// ---- output layout (floats, concatenated in return order) ----
#define OUT_XQ   ((size_t)0)
#define OUT_LOSS ((size_t)8388608)
#define OUT_IDX  ((size_t)8388609)
#define OUT_SCAL ((size_t)(8388609 + 32768))

__device__ inline double wave_sum_d(double v){ for (int d = 1; d < 64; d <<= 1) v += __shfl_xor(v, d); return v; }
__device__ inline unsigned umax_(unsigned a, unsigned b){ return a > b ? a : b; }
__device__ inline unsigned umin_(unsigned a, unsigned b){ return a < b ? a : b; }

// biased keys: value field is as_uint(sim+2.0) truncated to 19 bits (positive -> monotonic)
__device__ inline float kinvb(unsigned k){ return __uint_as_float(k & 0xFFFFE000u); }

__device__ inline void load16_lds(const void* g, void* l) {
    __builtin_amdgcn_global_load_lds(
        (const __attribute__((address_space(1))) unsigned int*)g,
        (__attribute__((address_space(3))) unsigned int*)l, 16, 0, 0);
}

// ---------------------------------------------------------------------------
// Phase 0: per-row L2 norms, f16 (RNE) normalized copies, fp64 inverse norms.
// ---------------------------------------------------------------------------
__global__ __launch_bounds__(256)
void prep_kernel(const float* __restrict__ x, const float* __restrict__ cb,
                 ushort* __restrict__ xbf, ushort* __restrict__ cbbf,
                 double* __restrict__ inv_cnorm) {
    int gw   = blockIdx.x * 4 + (threadIdx.x >> 6);
    int lane = threadIdx.x & 63;
    bool is_cb = gw >= B_ROWS;
    int row  = is_cb ? gw - B_ROWS : gw;
    const float* src = is_cb ? cb + (size_t)row * DIM : x + (size_t)row * DIM;
    ushort*      dst = is_cb ? cbbf + (size_t)row * DIM : xbf + (size_t)row * DIM;

    float4 v = ((const float4*)src)[lane];
    double ss = (double)v.x * v.x + (double)v.y * v.y + (double)v.z * v.z + (double)v.w * v.w;
    ss = wave_sum_d(ss);
    float inv = 1.f / fmaxf(sqrtf((float)ss), 1e-12f);
    ushort4 o;
    o.x = __half_as_ushort(__float2half(v.x * inv));
    o.y = __half_as_ushort(__float2half(v.y * inv));
    o.z = __half_as_ushort(__float2half(v.z * inv));
    o.w = __half_as_ushort(__float2half(v.w * inv));
    ((ushort4*)dst)[lane] = o;
    if (is_cb && lane == 0) inv_cnorm[row] = 1.0 / sqrt(ss);
}

// ---------------------------------------------------------------------------
// Phase 1: 256x256-tile f16 MFMA GEMM, BK=32, LDS=80KB -> TWO blocks/CU.
// The R1/R3 null result proved the single-block lockstep serializes
// MFMA / ds_read / TOP2-VALU; this round keeps the identical math and tile
// but shrinks LDS (Cs[2]+Xs[3], 16 KB each) so two independent blocks
// co-reside per CU and overlap each other's phases.
//  - X staged 2 K-steps ahead (HBM/L3 latency), C 1 ahead (L2-resident).
//  - one barrier + counted WVM(2) per K-step (WVM(0) only at the tail).
//  - 4-granule row swizzle: store src granule (t&3)^s(row), read granule
//    q^s(r16), s(r)=((r^(r>>2))&3)  => 2 lanes/bank-slot (free).
// Transposed mfma(cb,x); biased keys; exact top2 tournament; per-wave
// output 128(cb) x 64(x).
// ---------------------------------------------------------------------------
__global__ __launch_bounds__(512, 4)
void simmax_kernel(const ushort* __restrict__ xbf, const ushort* __restrict__ cbbf,
                   uint2* __restrict__ topinfo) {
    __shared__ __align__(16) ushort Cs[2][256 * 32];   // cb K-tiles, 16 KB each
    __shared__ __align__(16) ushort Xs[3][256 * 32];   // x  K-tiles, 16 KB each

    const int t    = threadIdx.x;
    const int xcd  = blockIdx.x & 7;
    const int lidx = blockIdx.x >> 3;
    const int bm   = xcd * 4 + (lidx & 3);             // 0..31  cb tile (XCD-chunked)
    const int bn   = lidx >> 2;                        // 0..127 x tile
    const int cn0  = bm * 256;
    const int rm0  = bn * 256;

    const int wid  = t >> 6, lane = t & 63;
    const int wm   = wid >> 2;                         // 0..1 : cb 128-band
    const int wn   = wid & 3;                          // 0..3 : x   64-band
    const int q    = lane >> 4, r16 = lane & 15;

    // ---- staging (DMA dest is strictly base + lane*16: ldst = t*16 bytes) ----
    const int srow4 = t >> 2;                          // 0..127
    const int sg    = (t & 3) ^ ((srow4 ^ (srow4 >> 2)) & 3);   // pre-swizzled src granule
    const ushort* cbsrc = cbbf + (size_t)(cn0 + srow4) * DIM + sg * 8;
    const ushort* xsrc  = xbf  + (size_t)(rm0 + srow4) * DIM + sg * 8;
    const int ldst = t * 8;                            // ushort units (= t*16 bytes)

    // ---- fragment read granule: q ^ s(r16), lane-constant ----
    const int grl = q ^ ((r16 ^ (r16 >> 2)) & 3);
    const int crb = (wm * 128 + r16) * 32 + grl * 8;   // + m2*512
    const int xrb = (wn * 64  + r16) * 32 + grl * 8;   // + n2*512

    f32x4 acc[8][4];                                   // [cb 16-tile][x 16-tile]
#pragma unroll
    for (int i = 0; i < 8; ++i)
#pragma unroll
        for (int j = 0; j < 4; ++j) acc[i][j] = (f32x4){2.f, 2.f, 2.f, 2.f};  // +2 bias

    f16x8 cfv[8], xfv[4];

#define SCHED0 __builtin_amdgcn_sched_barrier(0)
#define SBAR do { __builtin_amdgcn_s_barrier(); SCHED0; } while (0)
#define WVM(N) do { asm volatile("s_waitcnt vmcnt(" #N ")" ::: "memory"); SCHED0; } while (0)

// stage one 256x32 K-tile: 2 loads/thread (rows srow4, srow4+128)
#define ST_C(B,KT) do { \
    load16_lds(cbsrc + (KT)*32,                      &Cs[B][ldst]); \
    load16_lds(cbsrc + (size_t)128*DIM + (KT)*32,    &Cs[B][ldst + 4096]); \
} while (0)
#define ST_X(B,KT) do { \
    load16_lds(xsrc  + (KT)*32,                      &Xs[B][ldst]); \
    load16_lds(xsrc  + (size_t)128*DIM + (KT)*32,    &Xs[B][ldst + 4096]); \
} while (0)

// exact top2 tournament over 16 keys, then cross-q merge (keys globally unique)
#define TOP2(B2, NI, M1O, M2O) do { \
    const unsigned cbb_ = (unsigned)(cb0 - (B2) * 64); \
    unsigned k_[16]; \
    _Pragma("unroll") \
    for (int m2_ = 0; m2_ < 4; ++m2_) \
    _Pragma("unroll") \
    for (int r_ = 0; r_ < 4; ++r_) \
        k_[m2_*4+r_] = (__float_as_uint(acc[(B2)*4 + m2_][NI][r_]) & 0xFFFFE000u) \
                     | (cbb_ - (unsigned)(m2_*16 + r_)); \
    unsigned h0_[8], l0_[8]; \
    _Pragma("unroll") \
    for (int i_ = 0; i_ < 8; ++i_) { h0_[i_] = umax_(k_[2*i_], k_[2*i_+1]); l0_[i_] = umin_(k_[2*i_], k_[2*i_+1]); } \
    unsigned h1_[4], l1_[4]; \
    _Pragma("unroll") \
    for (int i_ = 0; i_ < 4; ++i_) { h1_[i_] = umax_(h0_[2*i_], h0_[2*i_+1]); l1_[i_] = umin_(h0_[2*i_], h0_[2*i_+1]); } \
    unsigned h2a_ = umax_(h1_[0], h1_[1]), l2a_ = umin_(h1_[0], h1_[1]); \
    unsigned h2b_ = umax_(h1_[2], h1_[3]), l2b_ = umin_(h1_[2], h1_[3]); \
    unsigned m1_  = umax_(h2a_, h2b_); \
    unsigned lt_  = umin_(h2a_, h2b_); \
    unsigned s0_  = umax_(umax_(umax_(l0_[0], l0_[1]), umax_(l0_[2], l0_[3])), \
                          umax_(umax_(l0_[4], l0_[5]), umax_(l0_[6], l0_[7]))); \
    unsigned s1_  = umax_(umax_(l1_[0], l1_[1]), umax_(l1_[2], l1_[3])); \
    unsigned m2v_ = umax_(umax_(s0_, s1_), umax_(umax_(l2a_, l2b_), lt_)); \
    _Pragma("unroll") \
    for (int d_ = 16; d_ < 64; d_ <<= 1) { \
        unsigned o1_ = (unsigned)__shfl_xor((int)m1_, d_); \
        unsigned o2_ = (unsigned)__shfl_xor((int)m2v_, d_); \
        unsigned lo_ = m1_ < o1_ ? m1_ : o1_; \
        m2v_ = umax_(umax_(m2v_, o2_), lo_); \
        m1_  = umax_(m1_, o1_); \
    } \
    M1O = m1_; M2O = m2v_; \
} while (0)

    // ---------------- prologue: C0, X0 staged; X1 in flight ----------------
    ST_C(0, 0);        // 2 loads
    ST_X(0, 0);        // 2 loads
    ST_X(1, 1);        // 2 loads
    WVM(2);            // C0, X0 landed; X1 flying
    SBAR;

#pragma unroll
    for (int kt = 0; kt < 8; ++kt) {
        const int curC = kt & 1;
        // stage ahead: C one K-step, X two K-steps
        if (kt < 7) ST_C(curC ^ 1, kt + 1);
        if (kt < 6) ST_X((kt + 2) % 3, kt + 2);
        // fragments for this K-step (compiler inserts counted lgkmcnt)
#pragma unroll
        for (int m2 = 0; m2 < 8; ++m2)
            cfv[m2] = *(const f16x8*)&Cs[curC][crb + m2 * 512];
#pragma unroll
        for (int n2 = 0; n2 < 4; ++n2)
            xfv[n2] = *(const f16x8*)&Xs[kt % 3][xrb + n2 * 512];
        __builtin_amdgcn_s_setprio(1);
#pragma unroll
        for (int m2 = 0; m2 < 8; ++m2)
#pragma unroll
            for (int n2 = 0; n2 < 4; ++n2)
                acc[m2][n2] = __builtin_amdgcn_mfma_f32_16x16x32_f16(
                    cfv[m2], xfv[n2], acc[m2][n2], 0, 0, 0);
        __builtin_amdgcn_s_setprio(0);
        if (kt < 6)      { WVM(2); SBAR; }   // next K-step's C/X landed
        else if (kt == 6){ WVM(0); SBAR; }   // tail: drain all
        // kt == 7: no staging, no barrier
    }

    // ---------------- epilogue: per-row top1/top2 per 64-col block ----------
    const int cb0 = 8191 - (cn0 + wm * 128 + q * 4);
#pragma unroll
    for (int ni = 0; ni < 4; ++ni) {
        unsigned r1a, r2a, r1b, r2b;
        TOP2(0, ni, r1a, r2a);
        TOP2(1, ni, r1b, r2b);
        if (q == 0) {
            const int rowg = rm0 + wn * 64 + ni * 16 + r16;
            uint4 o; o.x = r1a; o.y = r2a; o.z = r1b; o.w = r2b;
            *(uint4*)(topinfo + (size_t)rowg * NBLK64 + bm * 4 + wm * 2) = o;
        }
    }
#undef SCHED0
#undef SBAR
#undef WVM
#undef ST_C
#undef ST_X
#undef TOP2
}

// ---------------------------------------------------------------------------
// Phase 2 (fused decision + finalize). One wave per row. Keys are BIASED
// (sim+2); differences are bias-free so thresholds work unchanged; only the
// prescan threshold (unbiased f16 dots) subtracts 2.0.
// ---------------------------------------------------------------------------
__global__ __launch_bounds__(256)
void argmax_kernel(const float* __restrict__ x, const float* __restrict__ cb,
                   const ushort* __restrict__ xbf, const ushort* __restrict__ cbbf,
                   const uint2* __restrict__ topinfo,
                   const double* __restrict__ inv_cnorm,
                   float* __restrict__ out, float* __restrict__ loss_part) {
    __shared__ float lsum[4];
    const int w    = threadIdx.x >> 6;
    const int row  = blockIdx.x * 4 + w;
    const int lane = threadIdx.x & 63;

    uint4 tt = ((const uint4*)(topinfo + (size_t)row * NBLK64))[lane]; // blocks 2*lane, 2*lane+1
    unsigned k1[2] = {tt.x, tt.z};
    unsigned k2[2] = {tt.y, tt.w};

    unsigned W = umax_(k1[0], k1[1]);
    for (int d = 1; d < 64; d <<= 1) W = umax_(W, (unsigned)__shfl_xor((int)W, d));
    unsigned R = umax_((k1[0] == W) ? k2[0] : k1[0], (k1[1] == W) ? k2[1] : k1[1]);
    for (int d = 1; d < 64; d <<= 1) R = umax_(R, (unsigned)__shfl_xor((int)R, d));

    float v1w = kinvb(W);          // biased
    float rvf = kinvb(R);          // biased

    float4 xv = ((const float4*)(x + (size_t)row * DIM))[lane];

    int best_i;
    if (v1w - rvf > CERT_M) {                 // wave-uniform; bias cancels in difference
        best_i = 8191 - (int)(W & 0x1FFFu);
    } else {
        // ---- fallback: prescan + exact refine ----
        const int c = lane >> 3, e = lane & 7;
        float xh[32];
#pragma unroll
        for (int k4 = 0; k4 < 4; ++k4) {
            u16x8 hx = ((const u16x8*)(xbf + (size_t)row * DIM + e * 32))[k4];
#pragma unroll
            for (int j = 0; j < 8; ++j)
                xh[k4 * 8 + j] = __half2float(__ushort_as_half((ushort)hx[j]));
        }

        double best_s = -1e300;
        int bi = 0x7fffffff;
        auto exact_eval = [&](int n) {
            float4 cv = ((const float4*)(cb + (size_t)n * DIM))[lane];
            double s = (double)xv.x * cv.x + (double)xv.y * cv.y +
                       (double)xv.z * cv.z + (double)xv.w * cv.w;
            s = wave_sum_d(s);
            s *= inv_cnorm[n];
            if (s > best_s || (s == best_s && n < bi)) { best_s = s; bi = n; }
        };

        const float thrblk = v1w - CERT_M;            // biased domain
        const float thrpre = v1w - 2.0f - PRE_M;      // unbiased for f16 prescan dots
        float v1f[2] = {kinvb(k1[0]), kinvb(k1[1])};  // biased
#pragma unroll
        for (int s = 0; s < 2; ++s) {
            unsigned long long bm = __ballot(v1f[s] >= thrblk);   // wave-uniform
            while (bm) {
                int src = __ffsll((unsigned long long)bm) - 1;
                bm &= bm - 1;
                int blk = src * 2 + s;
#pragma unroll 1
                for (int sub = 0; sub < 8; ++sub) {
                    int n = blk * 64 + sub * 8 + c;
                    float s0 = 0.f, s1 = 0.f, s2 = 0.f, s3 = 0.f;
#pragma unroll
                    for (int k4 = 0; k4 < 4; ++k4) {
                        u16x8 chv = ((const u16x8*)(cbbf + (size_t)n * DIM + e * 32))[k4];
#pragma unroll
                        for (int j = 0; j < 8; ++j) {
                            float cf = __half2float(__ushort_as_half((ushort)chv[j]));
                            float xf = xh[k4 * 8 + j];
                            if ((j & 3) == 0) s0 = fmaf(xf, cf, s0);
                            else if ((j & 3) == 1) s1 = fmaf(xf, cf, s1);
                            else if ((j & 3) == 2) s2 = fmaf(xf, cf, s2);
                            else s3 = fmaf(xf, cf, s3);
                        }
                    }
                    float ps = (s0 + s1) + (s2 + s3);
                    ps += __shfl_xor(ps, 1);
                    ps += __shfl_xor(ps, 2);
                    ps += __shfl_xor(ps, 4);
                    unsigned long long sv = __ballot(e == 0 && ps >= thrpre);
                    while (sv) {
                        int b = __ffsll((unsigned long long)sv) - 1;
                        sv &= sv - 1;
                        exact_eval(blk * 64 + sub * 8 + (b >> 3));
                    }
                }
            }
        }
        // wave argmax reduce
        for (int d = 1; d < 64; d <<= 1) {
            double os = __shfl_xor(best_s, d);
            int    oi = __shfl_xor(bi, d);
            if (os > best_s || (os == best_s && oi < bi)) { best_s = os; bi = oi; }
        }
        best_i = bi;
    }

    // ---- fused finalize ----
    float4 cv = ((const float4*)(cb + (size_t)best_i * DIM))[lane];
    float dot = xv.x * cv.x + xv.y * cv.y + xv.z * cv.z + xv.w * cv.w;
    float nsq = cv.x * cv.x + cv.y * cv.y + cv.z * cv.z + cv.w * cv.w;
    float xsq = xv.x * xv.x + xv.y * xv.y + xv.z * xv.z + xv.w * xv.w;
    for (int d = 1; d < 64; d <<= 1) {
        dot += __shfl_xor(dot, d);
        nsq += __shfl_xor(nsq, d);
        xsq += __shfl_xor(xsq, d);
    }
    float scalar = dot / (nsq + 1e-8f);
    float4 pj = {scalar * cv.x, scalar * cv.y, scalar * cv.z, scalar * cv.w};
    ((float4*)(out + OUT_XQ + (size_t)row * DIM))[lane] = pj;

    float pn = fmaxf(sqrtf(scalar * scalar * nsq), 1e-8f);
    float xn = fmaxf(sqrtf(xsq), 1e-8f);
    float commit = (scalar * dot) / (pn * xn);
    if (lane == 0) {
        lsum[w] = 1.f - commit;
        out[OUT_IDX + row]  = (float)best_i;
        out[OUT_SCAL + row] = scalar;
    }
    __syncthreads();
    if (threadIdx.x == 0)
        loss_part[blockIdx.x] = lsum[0] + lsum[1] + lsum[2] + lsum[3];
}

__global__ __launch_bounds__(256)
void loss_kernel(const float* __restrict__ part, float* __restrict__ out) {
    __shared__ float ws_[4];
    float s = 0.f;
    for (int i = threadIdx.x; i < 8192; i += 256) s += part[i];
    for (int d = 1; d < 64; d <<= 1) s += __shfl_xor(s, d);
    if ((threadIdx.x & 63) == 0) ws_[threadIdx.x >> 6] = s;
    __syncthreads();
    if (threadIdx.x == 0)
        out[OUT_LOSS] = 0.25f * (ws_[0] + ws_[1] + ws_[2] + ws_[3]) * (1.0f / 32768.0f);
}

// ---------------------------------------------------------------------------
extern "C" void kernel_launch(void* const* d_in, const int* in_sizes, int n_in,
                              void* d_out, int out_size, void* d_ws, size_t ws_size,
                              hipStream_t stream) {
    const float* x  = (const float*)d_in[0];
    const float* cb = (const float*)d_in[1];
    float* out = (float*)d_out;
    char*  ws  = (char*)d_ws;
    ushort* xbf     = (ushort*)(ws + WS_XBF);
    ushort* cbbf    = (ushort*)(ws + WS_CBBF);
    uint2*  topinfo = (uint2*)(ws + WS_TOPINFO);
    double* inv_cn  = (double*)(ws + WS_CNORM);
    float*  loss_part = (float*)(ws + WS_LPART);

    hipLaunchKernelGGL(prep_kernel, dim3((B_ROWS + 8192) / 4), dim3(256), 0, stream,
                       x, cb, xbf, cbbf, inv_cn);
    hipLaunchKernelGGL(simmax_kernel, dim3((B_ROWS / 256) * (8192 / 256)), dim3(512), 0, stream,
                       xbf, cbbf, topinfo);
    hipLaunchKernelGGL(argmax_kernel, dim3(B_ROWS / 4), dim3(256), 0, stream,
                       x, cb, xbf, cbbf, topinfo, inv_cn, out, loss_part);
    hipLaunchKernelGGL(loss_kernel, dim3(1), dim3(256), 0, stream, loss_part, out);
}

// Round 5
// 287.548 us; speedup vs baseline: 5.8145x; 5.8145x over previous
//
#include <hip/hip_runtime.h>
#include <hip/hip_bf16.h>
#include <hip/hip_fp16.h>
#include <cstdint>
#include <cstddef>

// Problem constants
#define B_ROWS 32768
#define DIM    256
#define NBLK64 128          // 64-wide column blocks per row (8192/64)
// Keys are built from BIASED sims (acc initialized to +1.25: key value = sim+1.25,
// in (0.24, 2.26) for any f16 sim >= -1-eps  => always positive => bit-monotonic).
// Margin audit (sound): 2*eps_f16 (2.26e-3) + 19-bit key truncation at value<2
// (9.8e-4; worst-case value in [2,2.26) only if sim>0.75: 1.95e-3)
//   => bound 3.24e-3 (worst 4.21e-3) < CERT_M = 4.5e-3.
// Candidate-set bound: true-best col's key >= v1w - 3.24e-3 > v1w - CERT_M = thrblk,
// so it is either a stored block-top1/top2 (direct eval) or hides in a block whose
// k2 >= thrblk (full scan).
#define CERT_M 4.5e-3f
#define PRE_M  3.0e-3f
#define KBIAS  1.25f

typedef _Float16 f16x8 __attribute__((ext_vector_type(8)));
typedef float    f32x4 __attribute__((ext_vector_type(4)));
typedef unsigned short u16x8 __attribute__((ext_vector_type(8)));

// ---- workspace layout (bytes) ----
#define WS_XBF     ((size_t)0)                    // 32768*256*2 = 16 MB (f16 normalized x)
#define WS_CBBF    ((size_t)16777216)             //  8192*256*2 =  4 MB (f16 normalized cb)
#define WS_TOPINFO ((size_t)20971520)             // 32768*128*8 = 32 MB {u32 k1, u32 k2}
#define WS_CNORM   ((size_t)54525952)             //  8192*8     = 64 KB (fp64 inverse norms)
#define WS_LROW    ((size_t)54591488)             // 32768*4     = 128 KB per-row loss

// ---- output layout (floats, concatenated in return order) ----
#define OUT_XQ   ((size_t)0)
#define OUT_LOSS ((size_t)8388608)
#define OUT_IDX  ((size_t)8388609)
#define OUT_SCAL ((size_t)(8388609 + 32768))

__device__ inline double wave_sum_d(double v){ for (int d = 1; d < 64; d <<= 1) v += __shfl_xor(v, d); return v; }
__device__ inline unsigned umax_(unsigned a, unsigned b){ return a > b ? a : b; }
__device__ inline unsigned umin_(unsigned a, unsigned b){ return a < b ? a : b; }

// biased keys: value field is as_uint(sim+1.25) truncated to 19 bits (positive -> monotonic)
__device__ inline float kinvb(unsigned k){ return __uint_as_float(k & 0xFFFFE000u); }

__device__ inline void load16_lds(const void* g, void* l) {
    __builtin_amdgcn_global_load_lds(
        (const __attribute__((address_space(1))) unsigned int*)g,
        (__attribute__((address_space(3))) unsigned int*)l, 16, 0, 0);
}

// ---------------------------------------------------------------------------
// Phase 0: per-row L2 norms, f16 (RNE) normalized copies, fp64 inverse norms.
// ---------------------------------------------------------------------------
__global__ __launch_bounds__(256)
void prep_kernel(const float* __restrict__ x, const float* __restrict__ cb,
                 ushort* __restrict__ xbf, ushort* __restrict__ cbbf,
                 double* __restrict__ inv_cnorm) {
    int gw   = blockIdx.x * 4 + (threadIdx.x >> 6);
    int lane = threadIdx.x & 63;
    bool is_cb = gw >= B_ROWS;
    int row  = is_cb ? gw - B_ROWS : gw;
    const float* src = is_cb ? cb + (size_t)row * DIM : x + (size_t)row * DIM;
    ushort*      dst = is_cb ? cbbf + (size_t)row * DIM : xbf + (size_t)row * DIM;

    float4 v = ((const float4*)src)[lane];
    double ss = (double)v.x * v.x + (double)v.y * v.y + (double)v.z * v.z + (double)v.w * v.w;
    ss = wave_sum_d(ss);
    float inv = 1.f / fmaxf(sqrtf((float)ss), 1e-12f);
    ushort4 o;
    o.x = __half_as_ushort(__float2half(v.x * inv));
    o.y = __half_as_ushort(__float2half(v.y * inv));
    o.z = __half_as_ushort(__float2half(v.z * inv));
    o.w = __half_as_ushort(__float2half(v.w * inv));
    ((ushort4*)dst)[lane] = o;
    if (is_cb && lane == 0) inv_cnorm[row] = 1.0 / sqrt(ss);
}

// ---------------------------------------------------------------------------
// Phase 1: 256x256-tile 8-phase f16 MFMA GEMM (proven R1 structure, 175 us).
// 512 threads = 8 waves (2 cb x 4 x). BK=64, 4 K-tiles (K=256), fully
// unrolled with counted vmcnt (never 0 in steady state). acc init = +1.25
// (sound key bias, see margin audit above); exact top2 via tournament.
// Per-wave output 128(cb) x 64(x). Transposed mfma(cb,x).
// ---------------------------------------------------------------------------
__global__ __launch_bounds__(512, 2)
void simmax_kernel(const ushort* __restrict__ xbf, const ushort* __restrict__ cbbf,
                   uint2* __restrict__ topinfo) {
    __shared__ __align__(16) ushort Cs[2][256 * 64];   // cb tiles, 2 buffers
    __shared__ __align__(16) ushort Xs[2][256 * 64];   // x  tiles, 2 buffers

    const int t    = threadIdx.x;
    // XCD-chunked swizzle: XCD owns 4 m-tiles (512KB cb slice, L2-resident) x all n.
    const int xcd  = blockIdx.x & 7;
    const int lidx = blockIdx.x >> 3;
    const int bm   = xcd * 4 + (lidx & 3);             // 0..31  (cb tile)
    const int bn   = lidx >> 2;                        // 0..127 (x tile)
    const int cn0  = bm * 256;
    const int rm0  = bn * 256;

    const int wid  = t >> 6, lane = t & 63;
    const int wm   = wid >> 2;                         // 0..1 : cb 128-band
    const int wn   = wid & 3;                          // 0..3 : x   64-band
    const int q    = lane >> 4, r16 = lane & 15;

    // staging indices (XOR-granule swizzle; proven 0-conflict)
    const int srow = t >> 3;                           // 0..63
    const int cpos = t & 7;
    const int csrc = cpos ^ (srow & 7);
    const ushort* cbsrc = cbbf + (size_t)(cn0 + srow) * DIM + csrc * 8;
    const ushort* xsrc  = xbf  + (size_t)(rm0 + srow) * DIM + csrc * 8;
    const int ldst = srow * 64 + cpos * 8;             // ushort units

    // fragment read bases
    const int g0  = q ^ (r16 & 7);                     // granule slot, kk=0
    const int g1  = g0 ^ 4;                            // kk=1
    const int crb = (wm * 128 + r16) * 64;
    const int xrb = (wn * 64  + r16) * 64;

    f32x4 acc[8][4];                                   // [cb 16-tile][x 16-tile]
#pragma unroll
    for (int i = 0; i < 8; ++i)
#pragma unroll
        for (int j = 0; j < 4; ++j) acc[i][j] = (f32x4){KBIAS, KBIAS, KBIAS, KBIAS};

    f16x8 cf[4][2], xf0[2][2], xf1[2][2];

#define SCHED0 __builtin_amdgcn_sched_barrier(0)
#define SBAR do { SCHED0; __builtin_amdgcn_s_barrier(); SCHED0; } while (0)
#define WLG0 do { asm volatile("s_waitcnt lgkmcnt(0)" ::: "memory"); SCHED0; } while (0)
#define WVM(N) do { asm volatile("s_waitcnt vmcnt(" #N ")" ::: "memory"); SCHED0; } while (0)

#define ST_C(B,KT,H) do { \
    load16_lds(cbsrc + ((H)*128     ) * DIM + (KT)*64, &Cs[B][ldst + ((H)*128     ) * 64]); \
    load16_lds(cbsrc + ((H)*128 + 64) * DIM + (KT)*64, &Cs[B][ldst + ((H)*128 + 64) * 64]); \
} while (0)
#define ST_X(B,KT,H) do { \
    load16_lds(xsrc  + ((H)*128     ) * DIM + (KT)*64, &Xs[B][ldst + ((H)*128     ) * 64]); \
    load16_lds(xsrc  + ((H)*128 + 64) * DIM + (KT)*64, &Xs[B][ldst + ((H)*128 + 64) * 64]); \
} while (0)

#define RD_C(HM,B) do { \
    _Pragma("unroll") \
    for (int m2_ = 0; m2_ < 4; ++m2_) { \
        const ushort* p_ = &Cs[B][crb + ((HM)*64 + m2_*16) * 64]; \
        cf[m2_][0] = *(const f16x8*)(p_ + g0 * 8); \
        cf[m2_][1] = *(const f16x8*)(p_ + g1 * 8); \
    } } while (0)
#define RD_X(DST,HN,B) do { \
    _Pragma("unroll") \
    for (int n2_ = 0; n2_ < 2; ++n2_) { \
        const ushort* p_ = &Xs[B][xrb + ((HN)*32 + n2_*16) * 64]; \
        DST[n2_][0] = *(const f16x8*)(p_ + g0 * 8); \
        DST[n2_][1] = *(const f16x8*)(p_ + g1 * 8); \
    } } while (0)

#define MMQ(HM,HN,XF) do { \
    __builtin_amdgcn_s_setprio(1); \
    _Pragma("unroll") \
    for (int m2_ = 0; m2_ < 4; ++m2_) \
    _Pragma("unroll") \
    for (int n2_ = 0; n2_ < 2; ++n2_) \
    _Pragma("unroll") \
    for (int kk_ = 0; kk_ < 2; ++kk_) \
        acc[(HM)*4 + m2_][(HN)*2 + n2_] = __builtin_amdgcn_mfma_f32_16x16x32_f16( \
            cf[m2_][kk_], XF[n2_][kk_], acc[(HM)*4 + m2_][(HN)*2 + n2_], 0, 0, 0); \
    __builtin_amdgcn_s_setprio(0); \
} while (0)

    // ---------------- prologue: T0 full + T1:X0 in flight ----------------
    ST_X(0,0,0); ST_X(0,0,1); ST_C(0,0,0); ST_C(0,0,1);   // 8 loads
    ST_X(1,1,0);                                          // 2 loads
    WVM(2); SBAR;                                         // T0 complete, T1:X0 flying

    // ---------------- tile 0 (buf0) ----------------
    RD_C(0,0); RD_X(xf0,0,0); ST_X(1,1,1); SBAR; WLG0; MMQ(0,0,xf0); SBAR;
    RD_X(xf1,1,0);            ST_C(1,1,0); SBAR; WLG0; MMQ(0,1,xf1); SBAR;
    RD_C(1,0);                ST_C(1,1,1); SBAR; WLG0; MMQ(1,1,xf1); SBAR;
    ST_X(0,2,0); WVM(2);                   SBAR;       MMQ(1,0,xf0); SBAR;   // T1 ready
    // ---------------- tile 1 (buf1) ----------------
    RD_C(0,1); RD_X(xf0,0,1); ST_X(0,2,1); SBAR; WLG0; MMQ(0,0,xf0); SBAR;
    RD_X(xf1,1,1);            ST_C(0,2,0); SBAR; WLG0; MMQ(0,1,xf1); SBAR;
    RD_C(1,1);                ST_C(0,2,1); SBAR; WLG0; MMQ(1,1,xf1); SBAR;
    ST_X(1,3,0); WVM(2);                   SBAR;       MMQ(1,0,xf0); SBAR;   // T2 ready
    // ---------------- tile 2 (buf0) ----------------
    RD_C(0,0); RD_X(xf0,0,0); ST_X(1,3,1); SBAR; WLG0; MMQ(0,0,xf0); SBAR;
    RD_X(xf1,1,0);            ST_C(1,3,0); SBAR; WLG0; MMQ(0,1,xf1); SBAR;
    RD_C(1,0);                ST_C(1,3,1); SBAR; WLG0; MMQ(1,1,xf1); SBAR;
    WVM(0);                                SBAR;       MMQ(1,0,xf0); SBAR;   // T3 ready (drain)
    // ---------------- tile 3 (buf1) ----------------
    RD_C(0,1); RD_X(xf0,0,1);              SBAR; WLG0; MMQ(0,0,xf0); SBAR;
    RD_X(xf1,1,1);                         SBAR; WLG0; MMQ(0,1,xf1); SBAR;
    RD_C(1,1);                             SBAR; WLG0; MMQ(1,1,xf1); SBAR;
                                                       MMQ(1,0,xf0);

    // ---------------- epilogue: per-row top1/top2 per 64-col block --------
    const int cb0 = 8191 - (cn0 + wm * 128 + q * 4);
#pragma unroll
    for (int ni = 0; ni < 4; ++ni) {
        unsigned r1v[2], r2v[2];
#pragma unroll
        for (int b2 = 0; b2 < 2; ++b2) {
            const unsigned cbb = (unsigned)(cb0 - b2 * 64);
            unsigned k[16];
#pragma unroll
            for (int m2 = 0; m2 < 4; ++m2)
#pragma unroll
                for (int r = 0; r < 4; ++r)
                    k[m2 * 4 + r] = (__float_as_uint(acc[b2 * 4 + m2][ni][r]) & 0xFFFFE000u)
                                  | (cbb - (unsigned)(m2 * 16 + r));
            // exact top2: tournament; 2nd max = max over all 15 losers
            unsigned h0[8], l0[8];
#pragma unroll
            for (int i = 0; i < 8; ++i) { h0[i] = umax_(k[2*i], k[2*i+1]); l0[i] = umin_(k[2*i], k[2*i+1]); }
            unsigned h1[4], l1[4];
#pragma unroll
            for (int i = 0; i < 4; ++i) { h1[i] = umax_(h0[2*i], h0[2*i+1]); l1[i] = umin_(h0[2*i], h0[2*i+1]); }
            unsigned h2a = umax_(h1[0], h1[1]), l2a = umin_(h1[0], h1[1]);
            unsigned h2b = umax_(h1[2], h1[3]), l2b = umin_(h1[2], h1[3]);
            unsigned m1  = umax_(h2a, h2b);
            unsigned lt  = umin_(h2a, h2b);
            unsigned s0  = umax_(umax_(umax_(l0[0], l0[1]), umax_(l0[2], l0[3])),
                                 umax_(umax_(l0[4], l0[5]), umax_(l0[6], l0[7])));
            unsigned s1  = umax_(umax_(l1[0], l1[1]), umax_(l1[2], l1[3]));
            unsigned m2v = umax_(umax_(s0, s1), umax_(umax_(l2a, l2b), lt));
            // cross-q merge (keys globally unique)
#pragma unroll
            for (int d = 16; d < 64; d <<= 1) {
                unsigned o1 = (unsigned)__shfl_xor((int)m1, d);
                unsigned o2 = (unsigned)__shfl_xor((int)m2v, d);
                unsigned lo = m1 < o1 ? m1 : o1;
                m2v = umax_(umax_(m2v, o2), lo);
                m1  = umax_(m1, o1);
            }
            r1v[b2] = m1; r2v[b2] = m2v;
        }
        if (q == 0) {
            const int rowg = rm0 + wn * 64 + ni * 16 + r16;
            uint4 o; o.x = r1v[0]; o.y = r2v[0]; o.z = r1v[1]; o.w = r2v[1];
            *(uint4*)(topinfo + (size_t)rowg * NBLK64 + bm * 4 + wm * 2) = o;
        }
    }
#undef SCHED0
#undef SBAR
#undef WLG0
#undef WVM
#undef ST_C
#undef ST_X
#undef RD_C
#undef RD_X
#undef MMQ
}

// ---------------------------------------------------------------------------
// Phase 2 (fused decision + finalize). One wave per row, no cross-wave
// coupling (per-row loss partials, no __syncthreads).
// Fallback uses the stored per-block top1/top2 keys as the candidate set:
//  - block with k2 < thrblk: only its top1 col can compete -> direct fp64 eval
//    of that col (no scan).
//  - block with k2 >= thrblk (rare: two near-ties in one block): full f16
//    prescan of the 64 cols, fp64 eval of passers (old path).
// Soundness: true-best col's key >= v1w - (2*eps16 + trunc) > thrblk.
// ---------------------------------------------------------------------------
__global__ __launch_bounds__(256)
void argmax_kernel(const float* __restrict__ x, const float* __restrict__ cb,
                   const ushort* __restrict__ xbf, const ushort* __restrict__ cbbf,
                   const uint2* __restrict__ topinfo,
                   const double* __restrict__ inv_cnorm,
                   float* __restrict__ out, float* __restrict__ loss_row) {
    const int w    = threadIdx.x >> 6;
    const int row  = blockIdx.x * 4 + w;
    const int lane = threadIdx.x & 63;

    uint4 tt = ((const uint4*)(topinfo + (size_t)row * NBLK64))[lane]; // blocks 2*lane, 2*lane+1
    unsigned k1[2] = {tt.x, tt.z};
    unsigned k2[2] = {tt.y, tt.w};

    unsigned W = umax_(k1[0], k1[1]);
    for (int d = 1; d < 64; d <<= 1) W = umax_(W, (unsigned)__shfl_xor((int)W, d));
    unsigned R = umax_((k1[0] == W) ? k2[0] : k1[0], (k1[1] == W) ? k2[1] : k1[1]);
    for (int d = 1; d < 64; d <<= 1) R = umax_(R, (unsigned)__shfl_xor((int)R, d));

    float v1w = kinvb(W);          // biased
    float rvf = kinvb(R);          // biased

    float4 xv = ((const float4*)(x + (size_t)row * DIM))[lane];

    int best_i;
    if (v1w - rvf > CERT_M) {                 // wave-uniform; bias cancels in difference
        best_i = 8191 - (int)(W & 0x1FFFu);
    } else {
        double best_s = -1e300;
        int bi = 0x7fffffff;
        auto exact_eval = [&](int n) {
            float4 cv = ((const float4*)(cb + (size_t)n * DIM))[lane];
            double s = (double)xv.x * cv.x + (double)xv.y * cv.y +
                       (double)xv.z * cv.z + (double)xv.w * cv.w;
            s = wave_sum_d(s);
            s *= inv_cnorm[n];
            if (s > best_s || (s == best_s && n < bi)) { best_s = s; bi = n; }
        };

        const float thrblk = v1w - CERT_M;            // biased domain
        const float thrpre = v1w - KBIAS - PRE_M;     // unbiased for f16 prescan dots

        // classify blocks (all masks wave-uniform)
        unsigned long long evals[2], scans[2];
#pragma unroll
        for (int s = 0; s < 2; ++s) {
            float v1f = kinvb(k1[s]);
            float v2f = kinvb(k2[s]);
            bool p2 = v2f >= thrblk;
            evals[s] = __ballot((v1f >= thrblk) && !p2);
            scans[s] = __ballot(p2);
        }

        // ---- direct exact evals (typical: 2-4 total) ----
#pragma unroll
        for (int s = 0; s < 2; ++s) {
            unsigned long long bmv = evals[s];
            while (bmv) {
                int src = __ffsll(bmv) - 1;
                bmv &= bmv - 1;
                int kk = __shfl((int)k1[s], src);
                exact_eval(8191 - (kk & 0x1FFF));
            }
        }

        // ---- rare full scans (block may hide a 3rd candidate) ----
        if (scans[0] | scans[1]) {
            const int c = lane >> 3, e = lane & 7;
            float xh[32];
#pragma unroll
            for (int k4 = 0; k4 < 4; ++k4) {
                u16x8 hx = ((const u16x8*)(xbf + (size_t)row * DIM + e * 32))[k4];
#pragma unroll
                for (int j = 0; j < 8; ++j)
                    xh[k4 * 8 + j] = __half2float(__ushort_as_half((ushort)hx[j]));
            }
#pragma unroll
            for (int s = 0; s < 2; ++s) {
                unsigned long long bmv = scans[s];
                while (bmv) {
                    int src = __ffsll(bmv) - 1;
                    bmv &= bmv - 1;
                    int blk = src * 2 + s;
#pragma unroll 1
                    for (int sub = 0; sub < 8; ++sub) {
                        int n = blk * 64 + sub * 8 + c;
                        float s0 = 0.f, s1 = 0.f, s2 = 0.f, s3 = 0.f;
#pragma unroll
                        for (int k4 = 0; k4 < 4; ++k4) {
                            u16x8 chv = ((const u16x8*)(cbbf + (size_t)n * DIM + e * 32))[k4];
#pragma unroll
                            for (int j = 0; j < 8; ++j) {
                                float cf = __half2float(__ushort_as_half((ushort)chv[j]));
                                float xf = xh[k4 * 8 + j];
                                if ((j & 3) == 0) s0 = fmaf(xf, cf, s0);
                                else if ((j & 3) == 1) s1 = fmaf(xf, cf, s1);
                                else if ((j & 3) == 2) s2 = fmaf(xf, cf, s2);
                                else s3 = fmaf(xf, cf, s3);
                            }
                        }
                        float ps = (s0 + s1) + (s2 + s3);
                        ps += __shfl_xor(ps, 1);
                        ps += __shfl_xor(ps, 2);
                        ps += __shfl_xor(ps, 4);
                        unsigned long long sv = __ballot(e == 0 && ps >= thrpre);
                        while (sv) {
                            int b = __ffsll(sv) - 1;
                            sv &= sv - 1;
                            exact_eval(blk * 64 + sub * 8 + (b >> 3));
                        }
                    }
                }
            }
        }
        // wave argmax reduce
        for (int d = 1; d < 64; d <<= 1) {
            double os = __shfl_xor(best_s, d);
            int    oi = __shfl_xor(bi, d);
            if (os > best_s || (os == best_s && oi < bi)) { best_s = os; bi = oi; }
        }
        best_i = bi;
    }

    // ---- fused finalize ----
    float4 cv = ((const float4*)(cb + (size_t)best_i * DIM))[lane];
    float dot = xv.x * cv.x + xv.y * cv.y + xv.z * cv.z + xv.w * cv.w;
    float nsq = cv.x * cv.x + cv.y * cv.y + cv.z * cv.z + cv.w * cv.w;
    float xsq = xv.x * xv.x + xv.y * xv.y + xv.z * xv.z + xv.w * xv.w;
    for (int d = 1; d < 64; d <<= 1) {
        dot += __shfl_xor(dot, d);
        nsq += __shfl_xor(nsq, d);
        xsq += __shfl_xor(xsq, d);
    }
    float scalar = dot / (nsq + 1e-8f);
    float4 pj = {scalar * cv.x, scalar * cv.y, scalar * cv.z, scalar * cv.w};
    ((float4*)(out + OUT_XQ + (size_t)row * DIM))[lane] = pj;

    float pn = fmaxf(sqrtf(scalar * scalar * nsq), 1e-8f);
    float xn = fmaxf(sqrtf(xsq), 1e-8f);
    float commit = (scalar * dot) / (pn * xn);
    if (lane == 0) {
        loss_row[row] = 1.f - commit;
        out[OUT_IDX + row]  = (float)best_i;
        out[OUT_SCAL + row] = scalar;
    }
}

__global__ __launch_bounds__(256)
void loss_kernel(const float* __restrict__ part, float* __restrict__ out) {
    __shared__ float ws_[4];
    const float4* p4 = (const float4*)part;
    float s = 0.f;
    for (int i = threadIdx.x; i < 8192; i += 256) {
        float4 v = p4[i];
        s += (v.x + v.y) + (v.z + v.w);
    }
    for (int d = 1; d < 64; d <<= 1) s += __shfl_xor(s, d);
    if ((threadIdx.x & 63) == 0) ws_[threadIdx.x >> 6] = s;
    __syncthreads();
    if (threadIdx.x == 0)
        out[OUT_LOSS] = 0.25f * (ws_[0] + ws_[1] + ws_[2] + ws_[3]) * (1.0f / 32768.0f);
}

// ---------------------------------------------------------------------------
extern "C" void kernel_launch(void* const* d_in, const int* in_sizes, int n_in,
                              void* d_out, int out_size, void* d_ws, size_t ws_size,
                              hipStream_t stream) {
    const float* x  = (const float*)d_in[0];
    const float* cb = (const float*)d_in[1];
    float* out = (float*)d_out;
    char*  ws  = (char*)d_ws;
    ushort* xbf     = (ushort*)(ws + WS_XBF);
    ushort* cbbf    = (ushort*)(ws + WS_CBBF);
    uint2*  topinfo = (uint2*)(ws + WS_TOPINFO);
    double* inv_cn  = (double*)(ws + WS_CNORM);
    float*  loss_row = (float*)(ws + WS_LROW);

    hipLaunchKernelGGL(prep_kernel, dim3((B_ROWS + 8192) / 4), dim3(256), 0, stream,
                       x, cb, xbf, cbbf, inv_cn);
    hipLaunchKernelGGL(simmax_kernel, dim3((B_ROWS / 256) * (8192 / 256)), dim3(512), 0, stream,
                       xbf, cbbf, topinfo);
    hipLaunchKernelGGL(argmax_kernel, dim3(B_ROWS / 4), dim3(256), 0, stream,
                       x, cb, xbf, cbbf, topinfo, inv_cn, out, loss_row);
    hipLaunchKernelGGL(loss_kernel, dim3(1), dim3(256), 0, stream, loss_row, out);
}